// Round 8
// baseline (218.578 us; speedup 1.0000x reference)
//
#include <hip/hip_runtime.h>
#include <math.h>

// Problem constants (from reference): B=16, Q=3000, C=1203
#define NB 16
#define NQR 3000
#define NC 1203

typedef float f32x4 __attribute__((ext_vector_type(4)));

// ---------------------------------------------------------------------------
// Decision math — FROZEN from round 3 (passed, absmax = 1 bf16 ulp).
// Fast path: hw exp + rcp, +/-1e-5 band; band elements redo the reference's
// exact f32 op-chain: f32(exp_f64(-x)), IEEE f32 add, IEEE f32 div.
// ---------------------------------------------------------------------------
__device__ __forceinline__ int lane_proc(float x, float t,
                                         float* __restrict__ s,
                                         float* __restrict__ k) {
    float pf = __builtin_amdgcn_rcpf(1.0f + __expf(-x));
    bool kp;
    float sc;
    if (pf > t + 1e-5f) {
        kp = true;  sc = pf;
    } else if (pf < t - 1e-5f) {
        kp = false; sc = 0.0f;
    } else {
        float e32 = (float)exp(-(double)x);   // correctly-rounded f32 exp
        float p32 = 1.0f / (1.0f + e32);      // IEEE f32 add + div
        kp = (p32 >= t);
        sc = kp ? p32 : 0.0f;
    }
    *s = sc;
    *k = kp ? 1.0f : 0.0f;
    return kp ? 1 : 0;
}

// ---------------------------------------------------------------------------
// Kernel 1: partial max of logits over a Q-chunk, per (b,c).
// grid: (5, nb_chunk, nz), block 256; b = blockIdx.y + b0.
// ---------------------------------------------------------------------------
__global__ void k_partial_max(const float* __restrict__ logits,
                              float* __restrict__ partial,
                              int qc, int b0) {
    int c = blockIdx.x * blockDim.x + threadIdx.x;
    int b = blockIdx.y + b0;
    int z = blockIdx.z;
    if (c >= NC) return;
    int q0 = z * qc;
    int q1 = min(NQR, q0 + qc);
    float m = -INFINITY;
    const float* p = logits + ((size_t)(b * NQR + q0)) * NC + c;
    int q = q0;
    for (; q + 8 <= q1; q += 8) {
        float a0 = p[0];
        float a1 = p[NC];
        float a2 = p[2 * NC];
        float a3 = p[3 * NC];
        float a4 = p[4 * NC];
        float a5 = p[5 * NC];
        float a6 = p[6 * NC];
        float a7 = p[7 * NC];
        float m01 = fmaxf(a0, a1), m23 = fmaxf(a2, a3);
        float m45 = fmaxf(a4, a5), m67 = fmaxf(a6, a7);
        m = fmaxf(m, fmaxf(fmaxf(m01, m23), fmaxf(m45, m67)));
        p += 8 * NC;
    }
    for (; q < q1; ++q) {
        m = fmaxf(m, *p);
        p += NC;
    }
    partial[((size_t)z * NB + b) * NC + c] = m;
}

// ---------------------------------------------------------------------------
// Kernel 2: combine partial maxes -> f32-chain threshold (frozen numerics).
// ---------------------------------------------------------------------------
__global__ void k_thresh(const float* __restrict__ partial,
                         const int* __restrict__ cls_present,
                         float* __restrict__ thrf,
                         int nz, int b0) {
    int c = blockIdx.x * blockDim.x + threadIdx.x;
    int b = blockIdx.y + b0;
    if (c >= NC) return;
    float m = -INFINITY;
    for (int z = 0; z < nz; ++z)
        m = fmaxf(m, partial[((size_t)z * NB + b) * NC + c]);
    float t;
    if (cls_present[b * NC + c]) {
        float e32  = (float)exp(-(double)m);
        float ptop = 1.0f / (1.0f + e32);
        t = 0.5f * ptop;
    } else {
        t = INFINITY;
    }
    thrf[(size_t)b * NC + c] = t;
}

// ---------------------------------------------------------------------------
// Kernel 3: elementwise pass, ONE WAVE PER ROW. Row byte base = row*4812:
// head = row&3 scalars, 300 aligned f32x4 vectors, (3-head) tail scalars.
// Plain loads (cache the pass1-resident logits), NT stores (write-once).
// Depth-2 rotating prefetch: next iteration's vector issued before current
// compute — +4 VGPRs only (round-7 lesson: depth-5 bookkeeping cost more
// than its ILP bought).
// ---------------------------------------------------------------------------
__global__ __launch_bounds__(256) void k_main(const float* __restrict__ logits,
                                              const float* __restrict__ boxes,
                                              const float* __restrict__ thrf,
                                              float* __restrict__ scores,
                                              float* __restrict__ keep,
                                              float* __restrict__ boxes_out,
                                              int row0) {
    int wid  = threadIdx.x >> 6;
    int lane = threadIdx.x & 63;
    int row  = row0 + blockIdx.x * 4 + wid;
    int b    = row / NQR;

    const float* lrow = logits + (size_t)row * NC;
    const float* tf   = thrf + (size_t)b * NC;
    float* srow = scores + (size_t)row * NC;
    float* krow = keep + (size_t)row * NC;

    int head = row & 3;
    int any = 0;
    float sv, kv;

    // head scalars (0..head-1)
    if (lane < head) {
        int c = lane;
        any |= lane_proc(lrow[c], tf[c], &sv, &kv);
        __builtin_nontemporal_store(sv, srow + c);
        __builtin_nontemporal_store(kv, krow + c);
    }

    // body: 300 f32x4 vectors, depth-2 rotating prefetch
    f32x4 cur = *(const f32x4*)(lrow + head + 4 * lane);   // lane < 64 <= 300
#pragma unroll
    for (int i = 0; i < 5; ++i) {
        int vn = lane + 64 * (i + 1);
        f32x4 nxt;
        if (i < 4 && vn < 300)
            nxt = *(const f32x4*)(lrow + head + 4 * vn);
        int v = lane + 64 * i;
        if (v < 300) {
            int c = head + 4 * v;
            f32x4 s4, k4;
            float s0, s1, s2, s3, k0, k1, k2, k3;
            any |= lane_proc(cur.x, tf[c + 0], &s0, &k0);
            any |= lane_proc(cur.y, tf[c + 1], &s1, &k1);
            any |= lane_proc(cur.z, tf[c + 2], &s2, &k2);
            any |= lane_proc(cur.w, tf[c + 3], &s3, &k3);
            s4 = (f32x4){s0, s1, s2, s3};
            k4 = (f32x4){k0, k1, k2, k3};
            __builtin_nontemporal_store(s4, (f32x4*)(srow + c));
            __builtin_nontemporal_store(k4, (f32x4*)(krow + c));
        }
        cur = nxt;
    }

    // tail scalars (count = 3 - head)
    if (lane < 3 - head) {
        int c = head + 1200 + lane;
        any |= lane_proc(lrow[c], tf[c], &sv, &kv);
        __builtin_nontemporal_store(sv, srow + c);
        __builtin_nontemporal_store(kv, krow + c);
    }

    unsigned long long m = __ballot(any);
    if (lane == 0) {
        float mm = m ? 1.0f : 0.0f;
        f32x4 bx = *(const f32x4*)(boxes + (size_t)row * 4);
        f32x4 o = bx * mm;
        *(f32x4*)(boxes_out + (size_t)row * 4) = o;
    }
}

extern "C" void kernel_launch(void* const* d_in, const int* in_sizes, int n_in,
                              void* d_out, int out_size, void* d_ws, size_t ws_size,
                              hipStream_t stream) {
    const float* logits      = (const float*)d_in[0];  // [B,Q,C] f32
    const float* boxes       = (const float*)d_in[1];  // [B,Q,4] f32
    // d_in[2] = target_sizes (unused by reference math)
    const int*   cls_present = (const int*)d_in[3];    // [B,C] 0/1

    float* scores    = (float*)d_out;                       // [B,Q,C]
    float* keep      = scores + (size_t)NB * NQR * NC;      // [B,Q,C]
    float* boxes_out = keep + (size_t)NB * NQR * NC;        // [B,Q,4]

    // Workspace layout: partial[nz][B][C] f32 | thrf[B][C] f32
    int nz = 25;
    while (nz > 1 && ((size_t)nz + 1) * NB * NC * sizeof(float) > ws_size)
        nz /= 2;
    float* partial = (float*)d_ws;
    float* thrf    = partial + (size_t)nz * NB * NC;
    int qc = (NQR + nz - 1) / nz;

    // Chunked interleave over batches: pass1 -> thresh -> k_main per chunk so
    // k_main's logits re-read happens while the chunk is still L3-resident
    // (round-6 probe showed ~50% of the re-read was missing at full size).
    const int bsplit[4] = {0, 6, 11, 16};
    for (int ch = 0; ch < 3; ++ch) {
        int b0 = bsplit[ch];
        int nb = bsplit[ch + 1] - b0;

        dim3 gmax(5, nb, nz);
        k_partial_max<<<gmax, 256, 0, stream>>>(logits, partial, qc, b0);

        dim3 gthr(5, nb);
        k_thresh<<<gthr, 256, 0, stream>>>(partial, cls_present, thrf, nz, b0);

        k_main<<<nb * NQR / 4, 256, 0, stream>>>(logits, boxes, thrf,
                                                 scores, keep, boxes_out,
                                                 b0 * NQR);
    }
}

// Round 9
// 190.878 us; speedup vs baseline: 1.1451x; 1.1451x over previous
//
#include <hip/hip_runtime.h>
#include <math.h>

// Problem constants (from reference): B=16, Q=3000, C=1203
#define NB 16
#define NQR 3000
#define NC 1203

typedef float f32x4 __attribute__((ext_vector_type(4)));

// ---------------------------------------------------------------------------
// Decision math — FROZEN from round 3 (passed, absmax = 1 bf16 ulp).
// Fast path: hw exp + rcp, +/-1e-5 band; band elements redo the reference's
// exact f32 op-chain: f32(exp_f64(-x)), IEEE f32 add, IEEE f32 div.
// ---------------------------------------------------------------------------
__device__ __forceinline__ int lane_proc(float x, float t,
                                         float* __restrict__ s,
                                         float* __restrict__ k) {
    float pf = __builtin_amdgcn_rcpf(1.0f + __expf(-x));
    bool kp;
    float sc;
    if (pf > t + 1e-5f) {
        kp = true;  sc = pf;
    } else if (pf < t - 1e-5f) {
        kp = false; sc = 0.0f;
    } else {
        float e32 = (float)exp(-(double)x);   // correctly-rounded f32 exp
        float p32 = 1.0f / (1.0f + e32);      // IEEE f32 add + div
        kp = (p32 >= t);
        sc = kp ? p32 : 0.0f;
    }
    *s = sc;
    *k = kp ? 1.0f : 0.0f;
    return kp ? 1 : 0;
}

// ---------------------------------------------------------------------------
// Kernel 1: partial max of logits over a Q-chunk, per (b,c).
// grid: (ceil(C/256), B, nz), block 256. Lanes read adjacent c (coalesced);
// q-loop unrolled x8 -> 32 B/lane in flight.  [R5 structure, unchanged]
// ---------------------------------------------------------------------------
__global__ void k_partial_max(const float* __restrict__ logits,
                              float* __restrict__ partial,
                              int qc) {
    int c = blockIdx.x * blockDim.x + threadIdx.x;
    int b = blockIdx.y;
    int z = blockIdx.z;
    if (c >= NC) return;
    int q0 = z * qc;
    int q1 = min(NQR, q0 + qc);
    float m = -INFINITY;
    const float* p = logits + ((size_t)(b * NQR + q0)) * NC + c;
    int q = q0;
    for (; q + 8 <= q1; q += 8) {
        float a0 = p[0];
        float a1 = p[NC];
        float a2 = p[2 * NC];
        float a3 = p[3 * NC];
        float a4 = p[4 * NC];
        float a5 = p[5 * NC];
        float a6 = p[6 * NC];
        float a7 = p[7 * NC];
        float m01 = fmaxf(a0, a1), m23 = fmaxf(a2, a3);
        float m45 = fmaxf(a4, a5), m67 = fmaxf(a6, a7);
        m = fmaxf(m, fmaxf(fmaxf(m01, m23), fmaxf(m45, m67)));
        p += 8 * NC;
    }
    for (; q < q1; ++q) {
        m = fmaxf(m, *p);
        p += NC;
    }
    partial[((size_t)z * NB + b) * NC + c] = m;
}

// ---------------------------------------------------------------------------
// Kernel 2: combine partial maxes -> f32-chain threshold (frozen numerics).
// ---------------------------------------------------------------------------
__global__ void k_thresh(const float* __restrict__ partial,
                         const int* __restrict__ cls_present,
                         float* __restrict__ thrf,
                         int nz) {
    int c = blockIdx.x * blockDim.x + threadIdx.x;
    int b = blockIdx.y;
    if (c >= NC) return;
    float m = -INFINITY;
    for (int z = 0; z < nz; ++z)
        m = fmaxf(m, partial[((size_t)z * NB + b) * NC + c]);
    float t;
    if (cls_present[b * NC + c]) {
        float e32  = (float)exp(-(double)m);
        float ptop = 1.0f / (1.0f + e32);
        t = 0.5f * ptop;
    } else {
        t = INFINITY;
    }
    thrf[(size_t)b * NC + c] = t;
}

// ---------------------------------------------------------------------------
// Kernel 3: elementwise pass, ONE WAVE PER ROW (4 waves/block). Exact R5
// structure (simple loop, plain logits loads, NT stores) with ONE change:
// the 1203 per-class thresholds are staged in LDS once per block. All 4
// rows of a block share the same batch b (3000 % 4 == 0, so batch
// boundaries fall on block boundaries). This cuts the inner loop from
// 5 global load instructions per 16 B of data (1 vector + 4 misaligned
// scalar tf reads) to 1 global load + 4 LDS reads.
// ---------------------------------------------------------------------------
__global__ __launch_bounds__(256) void k_main(const float* __restrict__ logits,
                                              const float* __restrict__ boxes,
                                              const float* __restrict__ thrf,
                                              float* __restrict__ scores,
                                              float* __restrict__ keep,
                                              float* __restrict__ boxes_out) {
    int wid  = threadIdx.x >> 6;
    int lane = threadIdx.x & 63;
    int row  = blockIdx.x * 4 + wid;          // grid sized exactly: 48000 rows
    int b    = row / NQR;                     // same for all 4 waves in block

    __shared__ float tsh[NC];
    {
        const float* tf = thrf + (size_t)b * NC;
        for (int i = threadIdx.x; i < NC; i += 256)
            tsh[i] = tf[i];
    }
    __syncthreads();

    const float* lrow = logits + (size_t)row * NC;
    float* srow = scores + (size_t)row * NC;
    float* krow = keep + (size_t)row * NC;

    int head = row & 3;
    int any = 0;
    float sv, kv;

    // head scalars (0..head-1)
    if (lane < head) {
        int c = lane;
        any |= lane_proc(lrow[c], tsh[c], &sv, &kv);
        __builtin_nontemporal_store(sv, srow + c);
        __builtin_nontemporal_store(kv, krow + c);
    }

    // aligned f32x4 body: 300 vectors (simple R5 loop)
    for (int v = lane; v < 300; v += 64) {
        int c = head + 4 * v;
        f32x4 x4 = *(const f32x4*)(lrow + c);
        f32x4 s4, k4;
        float s0, s1, s2, s3, k0, k1, k2, k3;
        any |= lane_proc(x4.x, tsh[c + 0], &s0, &k0);
        any |= lane_proc(x4.y, tsh[c + 1], &s1, &k1);
        any |= lane_proc(x4.z, tsh[c + 2], &s2, &k2);
        any |= lane_proc(x4.w, tsh[c + 3], &s3, &k3);
        s4 = (f32x4){s0, s1, s2, s3};
        k4 = (f32x4){k0, k1, k2, k3};
        __builtin_nontemporal_store(s4, (f32x4*)(srow + c));
        __builtin_nontemporal_store(k4, (f32x4*)(krow + c));
    }

    // tail scalars (count = 3 - head)
    if (lane < 3 - head) {
        int c = head + 1200 + lane;
        any |= lane_proc(lrow[c], tsh[c], &sv, &kv);
        __builtin_nontemporal_store(sv, srow + c);
        __builtin_nontemporal_store(kv, krow + c);
    }

    unsigned long long m = __ballot(any);
    if (lane == 0) {
        float mm = m ? 1.0f : 0.0f;
        f32x4 bx = *(const f32x4*)(boxes + (size_t)row * 4);
        f32x4 o = bx * mm;
        *(f32x4*)(boxes_out + (size_t)row * 4) = o;
    }
}

extern "C" void kernel_launch(void* const* d_in, const int* in_sizes, int n_in,
                              void* d_out, int out_size, void* d_ws, size_t ws_size,
                              hipStream_t stream) {
    const float* logits      = (const float*)d_in[0];  // [B,Q,C] f32
    const float* boxes       = (const float*)d_in[1];  // [B,Q,4] f32
    // d_in[2] = target_sizes (unused by reference math)
    const int*   cls_present = (const int*)d_in[3];    // [B,C] 0/1

    float* scores    = (float*)d_out;                       // [B,Q,C]
    float* keep      = scores + (size_t)NB * NQR * NC;      // [B,Q,C]
    float* boxes_out = keep + (size_t)NB * NQR * NC;        // [B,Q,4]

    // Workspace layout: partial[nz][B][C] f32 | thrf[B][C] f32
    int nz = 25;
    while (nz > 1 && ((size_t)nz + 1) * NB * NC * sizeof(float) > ws_size)
        nz /= 2;
    float* partial = (float*)d_ws;
    float* thrf    = partial + (size_t)nz * NB * NC;
    int qc = (NQR + nz - 1) / nz;

    dim3 gmax((NC + 255) / 256, NB, nz);
    k_partial_max<<<gmax, 256, 0, stream>>>(logits, partial, qc);

    dim3 gthr((NC + 255) / 256, NB);
    k_thresh<<<gthr, 256, 0, stream>>>(partial, cls_present, thrf, nz);

    k_main<<<(NB * NQR) / 4, 256, 0, stream>>>(logits, boxes, thrf,
                                               scores, keep, boxes_out);
}